// Round 3
// baseline (98.086 us; speedup 1.0000x reference)
//
#include <hip/hip_runtime.h>

// 4-level lifting wavelet, fully fused, register-lifted, per-level thread counts.
// B=512 rows, N=65536. Block = (row, 4096-chunk) + 256-elem circular left halo.
// Per level: T threads each compute M pairs (8-pair recompute halo establishes
// the lifting state). avg outputs (and level-3 det) go DIRECTLY to global from
// registers; only det goes to LDS (it is the next level's input). LDS buffer
// placement makes det-write regions disjoint from the input region for levels
// 1-3, so only level 0 needs an internal barrier. 5 barriers total, 17.4 KB LDS.
#define BS    256
#define CHUNK 4096
#define HALO  256
#define NN    65536

// Work split: T active threads, M pairs each (T*M >= npairs), window W = M+8.
// avgG/detG are the chunk-local output bases; outputs stored at [p - discard].
template<int M, int T, bool SYNC, bool DET_LDS>
__device__ __forceinline__ void level_lift(
    float* lds, int inOff, int npairs, int detOff,
    float* __restrict__ avgG, float* __restrict__ detG, int discard,
    const float* __restrict__ P6, const float* __restrict__ U6, int tid)
{
  constexpr int W = M + 8;
  const bool act = (T == BS) || (tid < T);
  const int p0 = M * tid - 8;
  float in[2 * W];
  if (act) {
#pragma unroll
    for (int i = 0; i < W; ++i) {
      int p = p0 + i;
      p = p < 0 ? 0 : (p >= npairs ? npairs - 1 : p);
      float2 v = *(const float2*)&lds[inOff + 2 * p];
      in[2 * i] = v.x;
      in[2 * i + 1] = v.y;
    }
  }
  const float P0 = P6[0], P1 = P6[1], P2 = P6[2], P3 = P6[3], P4 = P6[4], P5 = P6[5];
  const float U0 = U6[0], U1 = U6[1], U2 = U6[2], U3 = U6[3], U4 = U6[4], U5 = U6[5];
  if (SYNC) __syncthreads();   // only needed when det region aliases input region
  if (act) {
    float e1 = 0, e2 = 0, d1 = 0, d2 = 0, a1 = 0, a2 = 0, f1 = 0, f2 = 0;
#pragma unroll
    for (int i = 0; i < W; ++i) {
      float e0 = in[2 * i], o0 = in[2 * i + 1];
      float d0 = o0 - (P0 * e0 + P1 * e1 + P2 * e2);
      float a0 = e0 + (U0 * d0 + U1 * d1 + U2 * d2);
      float f0 = d0 - (P3 * a0 + P4 * a1 + P5 * a2);
      float b0 = a0 + (U3 * f0 + U4 * f1 + U5 * f2);
      if (i >= 8) {
        int p = p0 + i;
        if (p < npairs) {
          if constexpr (DET_LDS) lds[detOff + p] = f0;
          if (p >= discard) {
            avgG[p - discard] = b0;
            if constexpr (!DET_LDS) detG[p - discard] = f0;
          }
        }
      }
      e2 = e1; e1 = e0; d2 = d1; d1 = d0; a2 = a1; a1 = a0; f2 = f1; f1 = f0;
    }
  }
}

__global__ __launch_bounds__(BS)
void wavelet_fused_kernel(const float* __restrict__ x,
                          const float* __restrict__ Pc,
                          const float* __restrict__ Uc,
                          float* __restrict__ out) {
  __shared__ __align__(16) float A[CHUNK + HALO];   // 4352 floats = 17.4 KB

  const int tid = threadIdx.x;
  const int cx  = blockIdx.x;   // chunk 0..15
  const int row = blockIdx.y;   // row 0..511
  const int S   = cx * CHUNK;

  // ---- load chunk + circular left halo ----
  const float4* x4 = (const float4*)(x + (size_t)row * NN);
  const int base4 = ((S - HALO) & (NN - 1)) >> 2;
  float4* A4 = (float4*)A;
  for (int i = tid; i < (CHUNK + HALO) / 4; i += BS)
    A4[i] = x4[(base4 + i) & (NN / 4 - 1)];
  __syncthreads();

  float* z0 = out + (size_t)row * 32768 + (S >> 1);
  float* z1 = out + 16777216 + (size_t)row * 16384 + (S >> 2);
  float* z2 = out + 25165824 + (size_t)row * 8192 + (S >> 3);
  float* z3 = out + 29360128 + (size_t)row * 4096 + (S >> 4);
  float* z4 = out + 31457280 + (size_t)row * 4096 + (S >> 4);

  // L0: input pairs = floats [0,4352); det -> floats [2176,4352) (aliases input
  // -> needs internal barrier); avg -> z0 direct.
  level_lift<9, 256, true, true>(A, 0, 2176, 2176, z0, nullptr, 128, Pc, Uc, tid);
  __syncthreads();

  // L1: input = floats [2176,4352); det -> [0,1088) (disjoint); avg -> z1.
  level_lift<9, 128, false, true>(A, 2176, 1088, 0, z1, nullptr, 64, Pc + 6, Uc + 6, tid);
  __syncthreads();

  // L2: input = floats [0,1088); det -> [1088,1632) (disjoint); avg -> z2.
  level_lift<9, 64, false, true>(A, 0, 544, 1088, z2, nullptr, 32, Pc + 12, Uc + 12, tid);
  __syncthreads();

  // L3: input = floats [1088,1632); avg -> z3, det -> z4, both direct.
  level_lift<5, 64, false, false>(A, 1088, 272, 0, z3, z4, 16, Pc + 18, Uc + 18, tid);
}

extern "C" void kernel_launch(void* const* d_in, const int* in_sizes, int n_in,
                              void* d_out, int out_size, void* d_ws, size_t ws_size,
                              hipStream_t stream) {
  const float* x  = (const float*)d_in[0];
  const float* Pc = (const float*)d_in[1];
  const float* Uc = (const float*)d_in[2];
  float* out = (float*)d_out;

  dim3 grid(NN / CHUNK, 512, 1);
  dim3 block(BS, 1, 1);
  wavelet_fused_kernel<<<grid, block, 0, stream>>>(x, Pc, Uc, out);
}

// Round 4
// 52.516 us; speedup vs baseline: 1.8677x; 1.8677x over previous
//
#include <hip/hip_runtime.h>

// 4-level lifting wavelet, fully fused, register-lifted, LDS-staged coalesced I/O.
// B=512 rows, N=65536. Block = (row, 4096-chunk) + 256-elem circular left halo.
// Per level: T threads each compute M pairs in registers (8-pair recompute halo
// establishes the lifting state), write avg+det back to LDS, and a disjoint
// thread range does the coalesced float4 store of the PREVIOUS level's output
// concurrently. R3 lesson: contiguous per-thread ownership (required by the
// recurrence) => direct global stores are 36B-stride uncoalesced; all output
// goes LDS -> float4 store. 7 barriers, 17.4 KB LDS.
#define BS    256
#define CHUNK 4096
#define HALO  256
#define NN    65536

// T active threads, M pairs each; input pairs at lds[inOff+2p], p in [0,npairs).
// avg -> lds[avgOff+p], det -> lds[detOff+p]. SYNC=true when outputs alias input
// (all inputs are register-resident before the internal barrier).
template<int M, int T, bool SYNC>
__device__ __forceinline__ void level_lift(float* lds, int inOff, int npairs,
                                           int avgOff, int detOff,
                                           const float* __restrict__ P6,
                                           const float* __restrict__ U6, int tid) {
  constexpr int W = M + 8;
  const bool act = (T == BS) || (tid < T);
  const int p0 = M * tid - 8;
  float in[2 * W];
  if (act) {
#pragma unroll
    for (int i = 0; i < W; ++i) {
      int p = p0 + i;
      p = p < 0 ? 0 : (p >= npairs ? npairs - 1 : p);
      float2 v = *(const float2*)&lds[inOff + 2 * p];
      in[2 * i] = v.x;
      in[2 * i + 1] = v.y;
    }
  }
  const float P0 = P6[0], P1 = P6[1], P2 = P6[2], P3 = P6[3], P4 = P6[4], P5 = P6[5];
  const float U0 = U6[0], U1 = U6[1], U2 = U6[2], U3 = U6[3], U4 = U6[4], U5 = U6[5];
  if (SYNC) __syncthreads();
  if (act) {
    float e1 = 0, e2 = 0, d1 = 0, d2 = 0, a1 = 0, a2 = 0, f1 = 0, f2 = 0;
#pragma unroll
    for (int i = 0; i < W; ++i) {
      float e0 = in[2 * i], o0 = in[2 * i + 1];
      float d0 = o0 - (P0 * e0 + P1 * e1 + P2 * e2);
      float a0 = e0 + (U0 * d0 + U1 * d1 + U2 * d2);
      float f0 = d0 - (P3 * a0 + P4 * a1 + P5 * a2);
      float b0 = a0 + (U3 * f0 + U4 * f1 + U5 * f2);
      if (i >= 8) {
        int p = p0 + i;
        if (p < npairs) {
          lds[avgOff + p] = b0;
          lds[detOff + p] = f0;
        }
      }
      e2 = e1; e1 = e0; d2 = d1; d1 = d0; a2 = a1; a1 = a0; f2 = f1; f1 = f0;
    }
  }
}

// Coalesced float4 store of n4 vectors using threads [t0, BS).
__device__ __forceinline__ void store4r(float* dst, const float* src, int n4,
                                        int tid, int t0) {
  if (tid >= t0) {
    const float4* s = (const float4*)src;
    float4* d = (float4*)dst;
    for (int i = tid - t0; i < n4; i += (BS - t0)) d[i] = s[i];
  }
}

__global__ __launch_bounds__(BS)
void wavelet_fused_kernel(const float* __restrict__ x,
                          const float* __restrict__ Pc,
                          const float* __restrict__ Uc,
                          float* __restrict__ out) {
  __shared__ __align__(16) float A[CHUNK + HALO];   // 4352 floats = 17.4 KB

  const int tid = threadIdx.x;
  const int cx  = blockIdx.x;   // chunk 0..15
  const int row = blockIdx.y;   // row 0..511
  const int S   = cx * CHUNK;

  // ---- load chunk + circular left halo ----
  const float4* x4 = (const float4*)(x + (size_t)row * NN);
  const int base4 = ((S - HALO) & (NN - 1)) >> 2;
  float4* A4 = (float4*)A;
  for (int i = tid; i < (CHUNK + HALO) / 4; i += BS)
    A4[i] = x4[(base4 + i) & (NN / 4 - 1)];
  __syncthreads();   // (1)

  float* z0 = out + (size_t)row * 32768 + (S >> 1);
  float* z1 = out + 16777216 + (size_t)row * 16384 + (S >> 2);
  float* z2 = out + 25165824 + (size_t)row * 8192 + (S >> 3);
  float* z3 = out + 29360128 + (size_t)row * 4096 + (S >> 4);
  float* z4 = out + 31457280 + (size_t)row * 4096 + (S >> 4);

  // L0: input pairs = floats [0,4352); avg -> [0,2176), det -> [2176,4352)
  // (aliases input -> internal barrier (2)).
  level_lift<9, 256, true>(A, 0, 2176, 0, 2176, Pc, Uc, tid);
  __syncthreads();   // (3) L0 writes -> readers below

  // Phase: store z0 (reads A[128..2176)) on threads [128,256)
  //        || L1 lift on threads [0,128): in [2176,4352), avg->[0,1088),
  //        det->[1088,2176). L1 writes overlap z0 reads -> barrier (4) between
  //        L1's write phase? No: L1 writes happen AFTER its reg-read of
  //        [2176,4352) only; they land in [0,2176) which z0 readers are
  //        reading. So keep them in separate barrier intervals:
  store4r(z0, A + 128, 512, tid, 128);
  __syncthreads();   // (4) z0 reads done before L1 writes begin
  level_lift<9, 128, false>(A, 2176, 1088, 0, 1088, Pc + 6, Uc + 6, tid);
  __syncthreads();   // (5)

  // store z1 (reads A[64..1088)) || L2 lift: in [1088,2176),
  // avg->[2176,2720), det->[2720,3264)  (all disjoint from z1 reads).
  store4r(z1, A + 64, 256, tid, 64);
  level_lift<9, 64, false>(A, 1088, 544, 2176, 2720, Pc + 12, Uc + 12, tid);
  __syncthreads();   // (6)

  // store z2 (reads A[2208..2720)) || L3 lift: in [2720,3264),
  // avg->[3264,3536), det->[3536,3808)  (disjoint).
  store4r(z2, A + 2208, 128, tid, 64);
  level_lift<5, 64, false>(A, 2720, 272, 3264, 3536, Pc + 18, Uc + 18, tid);
  __syncthreads();   // (7)

  store4r(z3, A + 3280, 64, tid, 0);
  store4r(z4, A + 3552, 64, tid, 0);
}

extern "C" void kernel_launch(void* const* d_in, const int* in_sizes, int n_in,
                              void* d_out, int out_size, void* d_ws, size_t ws_size,
                              hipStream_t stream) {
  const float* x  = (const float*)d_in[0];
  const float* Pc = (const float*)d_in[1];
  const float* Uc = (const float*)d_in[2];
  float* out = (float*)d_out;

  dim3 grid(NN / CHUNK, 512, 1);
  dim3 block(BS, 1, 1);
  wavelet_fused_kernel<<<grid, block, 0, stream>>>(x, Pc, Uc, out);
}

// Round 5
// 48.728 us; speedup vs baseline: 2.0129x; 1.0777x over previous
//
#include <hip/hip_runtime.h>

// 4-level lifting wavelet, fully fused, register-lifted, LDS-staged coalesced I/O.
// R5: (a) input staging via global_load_lds (16B direct-to-LDS; per-lane global
// address handles circular wrap, LDS dest linear) -- removes the VGPR-starved
// serial load chain (R4: VGPR_Count=20 meant ~1 load in flight per thread);
// (b) L1-L3 outputs in disjoint LDS regions (26.1 KB) -- one fewer barrier,
// z0 store fully overlaps L1 lift. 6 barriers total.
#define BS    256
#define CHUNK 4096
#define HALO  256
#define NN    65536
#define LDSF  6528   // floats

template<int M, int T, bool SYNC>
__device__ __forceinline__ void level_lift(float* lds, int inOff, int npairs,
                                           int avgOff, int detOff,
                                           const float* __restrict__ P6,
                                           const float* __restrict__ U6, int tid) {
  constexpr int W = M + 8;
  const bool act = (T == BS) || (tid < T);
  const int p0 = M * tid - 8;
  float in[2 * W];
  if (act) {
#pragma unroll
    for (int i = 0; i < W; ++i) {
      int p = p0 + i;
      p = p < 0 ? 0 : (p >= npairs ? npairs - 1 : p);
      float2 v = *(const float2*)&lds[inOff + 2 * p];
      in[2 * i] = v.x;
      in[2 * i + 1] = v.y;
    }
  }
  const float P0 = P6[0], P1 = P6[1], P2 = P6[2], P3 = P6[3], P4 = P6[4], P5 = P6[5];
  const float U0 = U6[0], U1 = U6[1], U2 = U6[2], U3 = U6[3], U4 = U6[4], U5 = U6[5];
  if (SYNC) __syncthreads();
  if (act) {
    float e1 = 0, e2 = 0, d1 = 0, d2 = 0, a1 = 0, a2 = 0, f1 = 0, f2 = 0;
#pragma unroll
    for (int i = 0; i < W; ++i) {
      float e0 = in[2 * i], o0 = in[2 * i + 1];
      float d0 = o0 - (P0 * e0 + P1 * e1 + P2 * e2);
      float a0 = e0 + (U0 * d0 + U1 * d1 + U2 * d2);
      float f0 = d0 - (P3 * a0 + P4 * a1 + P5 * a2);
      float b0 = a0 + (U3 * f0 + U4 * f1 + U5 * f2);
      if (i >= 8) {
        int p = p0 + i;
        if (p < npairs) {
          lds[avgOff + p] = b0;
          lds[detOff + p] = f0;
        }
      }
      e2 = e1; e1 = e0; d2 = d1; d1 = d0; a2 = a1; a1 = a0; f2 = f1; f1 = f0;
    }
  }
}

// Coalesced float4 store of n4 vectors using threads [t0, BS).
__device__ __forceinline__ void store4r(float* dst, const float* src, int n4,
                                        int tid, int t0) {
  if (tid >= t0) {
    const float4* s = (const float4*)src;
    float4* d = (float4*)dst;
    for (int i = tid - t0; i < n4; i += (BS - t0)) d[i] = s[i];
  }
}

__global__ __launch_bounds__(BS)
void wavelet_fused_kernel(const float* __restrict__ x,
                          const float* __restrict__ Pc,
                          const float* __restrict__ Uc,
                          float* __restrict__ out) {
  __shared__ __align__(16) float A[LDSF];   // 26.1 KB

  const int tid  = threadIdx.x;
  const int wave = tid >> 6;
  const int lane = tid & 63;
  const int cx   = blockIdx.x;   // chunk 0..15
  const int row  = blockIdx.y;   // row 0..511
  const int S    = cx * CHUNK;

  // ---- stage chunk + circular left halo straight into LDS ----
  // 1088 float4 slots = 17 wave-slices of 64; per slice: per-lane global addr
  // (wrap via pow2 mask), wave-uniform LDS base + lane*16 (HW-implicit).
  {
    const float4* x4 = (const float4*)(x + (size_t)row * NN);
    const int base4 = ((S - HALO) & (NN - 1)) >> 2;
    for (int s = wave; s < 17; s += 4) {
      const float4* g = &x4[(base4 + s * 64 + lane) & (NN / 4 - 1)];
      float* l = &A[s * 256];   // wave-uniform
      __builtin_amdgcn_global_load_lds(
          (const __attribute__((address_space(1))) void*)g,
          (__attribute__((address_space(3))) void*)l, 16, 0, 0);
    }
  }
  __syncthreads();   // (1) drains vmcnt

  float* z0 = out + (size_t)row * 32768 + (S >> 1);
  float* z1 = out + 16777216 + (size_t)row * 16384 + (S >> 2);
  float* z2 = out + 25165824 + (size_t)row * 8192 + (S >> 3);
  float* z3 = out + 29360128 + (size_t)row * 4096 + (S >> 4);
  float* z4 = out + 31457280 + (size_t)row * 4096 + (S >> 4);

  // L0: input pairs [0,4352); avg -> [0,2176), det -> [2176,4352)
  // (in-place; internal barrier (2) after reg-reads).
  level_lift<9, 256, true>(A, 0, 2176, 0, 2176, Pc, Uc, tid);
  __syncthreads();   // (3)

  // z0 store (threads 128-255, reads [128,2176)) || L1 (threads 0-127):
  // input [2176,4352) -> avg [4352,5440), det [5440,6528)  (disjoint).
  store4r(z0, A + 128, 512, tid, 128);
  level_lift<9, 128, false>(A, 2176, 1088, 4352, 5440, Pc + 6, Uc + 6, tid);
  __syncthreads();   // (4)

  // z1 store (threads 64-255, reads [4416,5440)) || L2 (threads 0-63):
  // input [5440,6528) -> avg [0,544), det [544,1088)  (disjoint).
  store4r(z1, A + 4416, 256, tid, 64);
  level_lift<9, 64, false>(A, 5440, 544, 0, 544, Pc + 12, Uc + 12, tid);
  __syncthreads();   // (5)

  // z2 store (threads 64-255, reads [32,544)) || L3 (threads 0-63):
  // input [544,1088) -> avg [1088,1360), det [1360,1632)  (disjoint).
  store4r(z2, A + 32, 128, tid, 64);
  level_lift<5, 64, false>(A, 544, 272, 1088, 1360, Pc + 18, Uc + 18, tid);
  __syncthreads();   // (6)

  store4r(z3, A + 1104, 64, tid, 0);   // avg pairs 16..272
  store4r(z4, A + 1376, 64, tid, 0);   // det pairs 16..272
}

extern "C" void kernel_launch(void* const* d_in, const int* in_sizes, int n_in,
                              void* d_out, int out_size, void* d_ws, size_t ws_size,
                              hipStream_t stream) {
  const float* x  = (const float*)d_in[0];
  const float* Pc = (const float*)d_in[1];
  const float* Uc = (const float*)d_in[2];
  float* out = (float*)d_out;

  dim3 grid(NN / CHUNK, 512, 1);
  dim3 block(BS, 1, 1);
  wavelet_fused_kernel<<<grid, block, 0, stream>>>(x, Pc, Uc, out);
}